// Round 1
// baseline (20942.845 us; speedup 1.0000x reference)
//
#include <hip/hip_runtime.h>
#include <math.h>

#define NN 8
#define CI 128
#define RR 256
#define AA 256
#define NHEADS 8
#define HCH 32
#define OO 256
#define HH 36
#define WW 36
#define NPIX (HH*WW)     // 1296
#define HV 34
#define WV 34
#define ND (HV*WV)       // 1156

#define QT 8
#define DT 128

// ---------------- xin = conv1x1(x, w_in) + b_in ----------------
__global__ __launch_bounds__(256) void k_xin(const float* __restrict__ x,
        const float* __restrict__ w_in, const float* __restrict__ b_in,
        float* __restrict__ xin) {
    int p = blockIdx.x * 256 + threadIdx.x;
    int r = blockIdx.y, n = blockIdx.z;
    if (p >= NPIX) return;
    const float* xp = x + (size_t)n * CI * NPIX + p;
    const float* wp = w_in + r * CI;
    float acc = b_in[r];
    #pragma unroll 8
    for (int i = 0; i < CI; i++) acc += wp[i] * xp[(size_t)i * NPIX];
    xin[((size_t)n * RR + r) * NPIX + p] = acc;
}

// ---------------- q = conv3x3_same(xin, w_qx) ----------------
__global__ __launch_bounds__(256) void k_conv_q(const float* __restrict__ xin,
        const float* __restrict__ w, float* __restrict__ q) {
    int p = blockIdx.x * 256 + threadIdx.x;
    int a = blockIdx.y, n = blockIdx.z;
    if (p >= NPIX) return;
    int y = p / WW, xx = p % WW;
    int offs[9]; float msk[9];
    #pragma unroll
    for (int ky = 0; ky < 3; ky++)
      #pragma unroll
      for (int kx = 0; kx < 3; kx++) {
        int yy = y + ky - 1, xc = xx + kx - 1;
        bool ok = (yy >= 0 && yy < HH && xc >= 0 && xc < WW);
        offs[ky*3+kx] = ok ? (yy*WW + xc) : 0;
        msk[ky*3+kx] = ok ? 1.f : 0.f;
      }
    const float* base = xin + (size_t)n * RR * NPIX;
    const float* wp = w + (size_t)a * RR * 9;
    float acc = 0.f;
    for (int r = 0; r < RR; r++) {
      const float* bp = base + (size_t)r * NPIX;
      const float* w9 = wp + r * 9;
      #pragma unroll
      for (int tt = 0; tt < 9; tt++)
        acc += w9[tt] * (msk[tt] * bp[offs[tt]]);
    }
    q[((size_t)n * AA + a) * NPIX + p] = acc;
}

// ---------------- k,v = conv3x3_valid(xin, w_kx/w_vx) ----------------
__global__ __launch_bounds__(256) void k_conv_kv(const float* __restrict__ xin,
        const float* __restrict__ wk, const float* __restrict__ wv,
        float* __restrict__ kout, float* __restrict__ vout) {
    int p = blockIdx.x * 256 + threadIdx.x;
    int a = blockIdx.y, n = blockIdx.z;
    if (p >= ND) return;
    int y = p / WV, xx = p % WV;
    const float* base = xin + (size_t)n * RR * NPIX + y * WW + xx;
    const float* wkp = wk + (size_t)a * RR * 9;
    const float* wvp = wv + (size_t)a * RR * 9;
    float ak = 0.f, av = 0.f;
    for (int r = 0; r < RR; r++) {
      const float* bp = base + (size_t)r * NPIX;
      #pragma unroll
      for (int ky = 0; ky < 3; ky++)
        #pragma unroll
        for (int kx = 0; kx < 3; kx++) {
          float xv = bp[ky*WW + kx];
          ak += wkp[r*9 + ky*3+kx] * xv;
          av += wvp[r*9 + ky*3+kx] * xv;
        }
    }
    kout[((size_t)n * AA + a) * ND + p] = ak;
    vout[((size_t)n * AA + a) * ND + p] = av;
}

// ---------------- attention per (n, h, 8-query block) ----------------
__global__ __launch_bounds__(256) void k_attn(const float* __restrict__ q,
        const float* __restrict__ k, const float* __restrict__ v,
        float* __restrict__ aOut) {
    __shared__ float sQ[HCH][QT];         // [32][8]
    __shared__ float sKV[HCH][DT + 1];    // [32][129]  (+1 pad: no bank conflicts)
    __shared__ float sS[QT][ND + 4];      // [8][1160] score rows
    __shared__ float sInv[QT];

    int t = threadIdx.x;
    int q0 = blockIdx.x * QT;
    int h = blockIdx.y, n = blockIdx.z;

    const float* Qp = q + ((size_t)n * AA + h * HCH) * NPIX;
    const float* Kp = k + ((size_t)n * AA + h * HCH) * ND;
    const float* Vp = v + ((size_t)n * AA + h * HCH) * ND;

    { // load Q block: 256 threads, 256 elements
      int c = t >> 3, ql = t & 7;
      sQ[c][ql] = Qp[(size_t)c * NPIX + q0 + ql];
    }
    __syncthreads();

    // phase 1: scores S[ql][d] = sum_c Q[c][ql]*K[c][d]
    for (int dc = 0; dc < ND; dc += DT) {
      for (int idx = t; idx < HCH * DT; idx += 256) {
        int c = idx / DT, dl = idx % DT;
        int d = dc + dl;
        sKV[c][dl] = (d < ND) ? Kp[(size_t)c * ND + d] : 0.f;
      }
      __syncthreads();
      int nd = min(DT, ND - dc);
      for (int s = t; s < QT * DT; s += 256) {
        int ql = s / DT, dl = s % DT;
        if (dl < nd) {
          float acc = 0.f;
          #pragma unroll
          for (int c = 0; c < HCH; c++) acc += sQ[c][ql] * sKV[c][dl];
          sS[ql][dc + dl] = acc;
        }
      }
      __syncthreads();
    }

    // phase 2: row softmax (32 lanes per row)
    {
      int row = t >> 5, l = t & 31;
      float m = -1e30f;
      for (int d = l; d < ND; d += 32) m = fmaxf(m, sS[row][d]);
      #pragma unroll
      for (int off = 16; off >= 1; off >>= 1) m = fmaxf(m, __shfl_xor(m, off, 32));
      float sum = 0.f;
      for (int d = l; d < ND; d += 32) {
        float e = __expf(sS[row][d] - m);
        sS[row][d] = e;
        sum += e;
      }
      #pragma unroll
      for (int off = 16; off >= 1; off >>= 1) sum += __shfl_xor(sum, off, 32);
      if (l == 0) sInv[row] = 1.f / sum;
    }
    __syncthreads();

    // phase 3: out[c][ql] = sum_d V[c][d] * P[ql][d]
    float acc = 0.f;
    int c = t & 31, ql = t >> 5;
    for (int dc = 0; dc < ND; dc += DT) {
      for (int idx = t; idx < HCH * DT; idx += 256) {
        int cc = idx / DT, dl = idx % DT;
        int d = dc + dl;
        sKV[cc][dl] = (d < ND) ? Vp[(size_t)cc * ND + d] : 0.f;
      }
      __syncthreads();
      int nd = min(DT, ND - dc);
      for (int dl = 0; dl < nd; dl++)
        acc += sKV[c][dl] * sS[ql][dc + dl];
      __syncthreads();
    }
    aOut[((size_t)n * AA + h * HCH + c) * NPIX + q0 + ql] = acc * sInv[ql];
}

// ---------------- gates -> hn (gf skipped: c_prev = 0) ----------------
__global__ __launch_bounds__(256) void k_gates(const float* __restrict__ aIn,
        const float* __restrict__ xin, const float* __restrict__ w_ga,
        const float* __restrict__ b_g, const float* __restrict__ w_gx,
        float* __restrict__ hn) {
    int p = blockIdx.x * 256 + threadIdx.x;
    int r = blockIdx.y, n = blockIdx.z;
    if (p >= NPIX) return;
    float gi = b_g[r], gg = b_g[r + 2*RR], go = b_g[r + 3*RR];
    const float* ap = aIn + (size_t)n * AA * NPIX + p;
    const float* wi = w_ga + (size_t)r * AA;
    const float* wg = w_ga + (size_t)(r + 2*RR) * AA;
    const float* wo = w_ga + (size_t)(r + 3*RR) * AA;
    for (int ch = 0; ch < AA; ch++) {
      float av = ap[(size_t)ch * NPIX];
      gi += wi[ch] * av; gg += wg[ch] * av; go += wo[ch] * av;
    }
    const float* xp = xin + (size_t)n * RR * NPIX + p;
    const float* wi2 = w_gx + (size_t)r * RR;
    const float* wg2 = w_gx + (size_t)(r + 2*RR) * RR;
    const float* wo2 = w_gx + (size_t)(r + 3*RR) * RR;
    for (int ch = 0; ch < RR; ch++) {
      float xv = xp[(size_t)ch * NPIX];
      gi += wi2[ch] * xv; gg += wg2[ch] * xv; go += wo2[ch] * xv;
    }
    float si = 1.f / (1.f + __expf(-gi));
    float cc = si * tanhf(gg);
    float so = 1.f / (1.f + __expf(-go));
    hn[((size_t)n * RR + r) * NPIX + p] = so * tanhf(cc);
}

// ---------------- out = conv1x1(hn, w_out) + b_out ----------------
__global__ __launch_bounds__(256) void k_out(const float* __restrict__ hn,
        const float* __restrict__ w_out, const float* __restrict__ b_out,
        float* __restrict__ out) {
    int p = blockIdx.x * 256 + threadIdx.x;
    int o = blockIdx.y, n = blockIdx.z;
    if (p >= NPIX) return;
    const float* hp = hn + (size_t)n * RR * NPIX + p;
    const float* wp = w_out + (size_t)o * RR;
    float acc = b_out[o];
    for (int r = 0; r < RR; r++) acc += wp[r] * hp[(size_t)r * NPIX];
    out[((size_t)n * OO + o) * NPIX + p] = acc;
}

extern "C" void kernel_launch(void* const* d_in, const int* in_sizes, int n_in,
                              void* d_out, int out_size, void* d_ws, size_t ws_size,
                              hipStream_t stream) {
    const float* x     = (const float*)d_in[0];
    const float* w_in  = (const float*)d_in[1];
    const float* b_in  = (const float*)d_in[2];
    const float* w_qx  = (const float*)d_in[3];
    // d_in[4] w_qh unused (h == 0)
    const float* w_kx  = (const float*)d_in[5];
    // d_in[6] w_kh unused
    const float* w_vx  = (const float*)d_in[7];
    // d_in[8] w_vh unused
    const float* w_ga  = (const float*)d_in[9];
    const float* b_g   = (const float*)d_in[10];
    const float* w_gx  = (const float*)d_in[11];
    // d_in[12] w_gh unused
    const float* w_out = (const float*)d_in[13];
    const float* b_out = (const float*)d_in[14];
    float* out = (float*)d_out;

    float* ws = (float*)d_ws;
    const size_t np = (size_t)NN * RR * NPIX;   // 2,654,208
    const size_t nd = (size_t)NN * AA * ND;     // 2,367,488
    float* xin = ws;            // [N][R][P]
    float* qb  = xin + np;      // [N][A][P]
    float* kb  = qb + np;       // [N][A][D]
    float* vb  = kb + nd;       // [N][A][D]
    float* ab  = vb + nd;       // [N][A][P]
    float* hnb = qb;            // reuse q slot (dead after attention)

    dim3 blk(256);
    k_xin    <<<dim3((NPIX+255)/256, RR, NN), blk, 0, stream>>>(x, w_in, b_in, xin);
    k_conv_q <<<dim3((NPIX+255)/256, AA, NN), blk, 0, stream>>>(xin, w_qx, qb);
    k_conv_kv<<<dim3((ND+255)/256,  AA, NN), blk, 0, stream>>>(xin, w_kx, w_vx, kb, vb);
    k_attn   <<<dim3(NPIX/QT, NHEADS, NN),   blk, 0, stream>>>(qb, kb, vb, ab);
    k_gates  <<<dim3((NPIX+255)/256, RR, NN), blk, 0, stream>>>(ab, xin, w_ga, b_g, w_gx, hnb);
    k_out    <<<dim3((NPIX+255)/256, OO, NN), blk, 0, stream>>>(hnb, w_out, b_out, out);
}

// Round 2
// 2275.785 us; speedup vs baseline: 9.2025x; 9.2025x over previous
//
#include <hip/hip_runtime.h>
#include <math.h>

#define NN 8
#define CI 128
#define RR 256
#define AA 256
#define NHEADS 8
#define HCH 32
#define OO 256
#define HH 36
#define WW 36
#define NPIX 1296
#define HV 34
#define WV 34
#define ND 1156

#define BK 32
#define LPAD 68   // LDS row stride (floats): %4==0 for float4 align, breaks pow2 conflicts
#define DT 128

// ================= tiled GEMM core macro (64x64 tile, 4x4/thread) =================
#define GEMM_CORE_1(ACC, XS, WS)                                                  \
  _Pragma("unroll")                                                               \
  for (int cc = 0; cc < BK; cc++) {                                               \
    float4 xv = *(const float4*)&XS[cc][tx*4];                                    \
    float4 wv = *(const float4*)&WS[cc][ty*4];                                    \
    ACC[0][0] += wv.x*xv.x; ACC[0][1] += wv.x*xv.y; ACC[0][2] += wv.x*xv.z; ACC[0][3] += wv.x*xv.w; \
    ACC[1][0] += wv.y*xv.x; ACC[1][1] += wv.y*xv.y; ACC[1][2] += wv.y*xv.z; ACC[1][3] += wv.y*xv.w; \
    ACC[2][0] += wv.z*xv.x; ACC[2][1] += wv.z*xv.y; ACC[2][2] += wv.z*xv.z; ACC[2][3] += wv.z*xv.w; \
    ACC[3][0] += wv.w*xv.x; ACC[3][1] += wv.w*xv.y; ACC[3][2] += wv.w*xv.z; ACC[3][3] += wv.w*xv.w; \
  }

// ---------------- 1x1 conv as GEMM: out[m][p] = sum_k w[m][k] in[k][p] + bias[m] --------
__global__ __launch_bounds__(256) void k_gemm1x1(const float* __restrict__ in,
        const float* __restrict__ w, const float* __restrict__ bias,
        float* __restrict__ out, int K) {
    __shared__ float Xs[BK][LPAD];
    __shared__ float Ws[BK][LPAD];
    int tid = threadIdx.x;
    int tx = tid & 15, ty = tid >> 4;
    int p0 = blockIdx.x * 64, m0 = blockIdx.y * 64, n = blockIdx.z;
    float acc[4][4] = {};
    for (int k0 = 0; k0 < K; k0 += BK) {
      for (int idx = tid; idx < 2048; idx += 256) {
        int cc = idx >> 6, pp = idx & 63;
        int p = p0 + pp;
        Xs[cc][pp] = (p < NPIX) ? in[((size_t)n*K + k0+cc)*NPIX + p] : 0.f;
      }
      for (int idx = tid; idx < 2048; idx += 256) {
        int aa = idx >> 5, cc = idx & 31;
        Ws[cc][aa] = w[(size_t)(m0+aa)*K + k0+cc];
      }
      __syncthreads();
      GEMM_CORE_1(acc, Xs, Ws)
      __syncthreads();
    }
    #pragma unroll
    for (int j = 0; j < 4; j++) {
      int m = m0 + ty*4 + j;
      float b = bias[m];
      #pragma unroll
      for (int i = 0; i < 4; i++) {
        int p = p0 + tx*4 + i;
        if (p < NPIX) out[((size_t)n*256 + m)*NPIX + p] = acc[j][i] + b;
      }
    }
}

// ---------------- 3x3 conv as implicit GEMM, K = 256*9 ----------------
template<bool SAME>
__global__ __launch_bounds__(256) void k_conv3x3(const float* __restrict__ xin,
        const float* __restrict__ w, float* __restrict__ out) {
    __shared__ float Xs[BK][LPAD];
    __shared__ float Ws[BK][LPAD];
    const int NP = SAME ? NPIX : ND;
    const int WO = SAME ? WW : WV;
    int tid = threadIdx.x;
    int tx = tid & 15, ty = tid >> 4;
    int p0 = blockIdx.x * 64, m0 = blockIdx.y * 64, n = blockIdx.z;
    float acc[4][4] = {};
    for (int k0 = 0; k0 < RR*9; k0 += BK) {
      for (int idx = tid; idx < 2048; idx += 256) {
        int cc = idx >> 6, pp = idx & 63;
        int k = k0 + cc;
        int r = k / 9, t = k - r*9;
        int ky = t / 3, kx = t - ky*3;
        int p = p0 + pp;
        float val = 0.f;
        if (p < NP) {
          int y = p / WO, xx = p - y*WO;
          int yy, xc;
          if (SAME) { yy = y + ky - 1; xc = xx + kx - 1; }
          else      { yy = y + ky;     xc = xx + kx;     }
          if (!SAME || (yy >= 0 && yy < HH && xc >= 0 && xc < WW))
            val = xin[((size_t)n*RR + r)*NPIX + yy*WW + xc];
        }
        Xs[cc][pp] = val;
      }
      for (int idx = tid; idx < 2048; idx += 256) {
        int aa = idx >> 5, cc = idx & 31;
        Ws[cc][aa] = w[(size_t)(m0+aa)*(RR*9) + k0+cc];
      }
      __syncthreads();
      GEMM_CORE_1(acc, Xs, Ws)
      __syncthreads();
    }
    #pragma unroll
    for (int j = 0; j < 4; j++) {
      int m = m0 + ty*4 + j;
      #pragma unroll
      for (int i = 0; i < 4; i++) {
        int p = p0 + tx*4 + i;
        if (p < NP) out[((size_t)n*AA + m)*NP + p] = acc[j][i];
      }
    }
}

// ---------------- flash attention: 64 threads, 2 queries/thread ----------------
__global__ __launch_bounds__(64) void k_attn(const float* __restrict__ qb,
        const float* __restrict__ kb, const float* __restrict__ vb,
        float* __restrict__ ab) {
    __shared__ float sK[DT][36];
    __shared__ float sV[DT][36];
    int tid = threadIdx.x;
    int h = blockIdx.y, n = blockIdx.z;
    int q0 = blockIdx.x * 128;
    int qA = q0 + tid, qB = q0 + 64 + tid;
    const float* Qp = qb + ((size_t)n*AA + h*HCH)*NPIX;
    const float* Kp = kb + ((size_t)n*AA + h*HCH)*ND;
    const float* Vp = vb + ((size_t)n*AA + h*HCH)*ND;
    int qAc = qA < NPIX ? qA : NPIX-1;
    int qBc = qB < NPIX ? qB : NPIX-1;
    float qra[32], qrb[32];
    #pragma unroll
    for (int c = 0; c < 32; c++) {
      qra[c] = Qp[(size_t)c*NPIX + qAc];
      qrb[c] = Qp[(size_t)c*NPIX + qBc];
    }
    float mA = -1e30f, sA = 0.f, mB = -1e30f, sB = 0.f;
    float accA[32] = {}, accB[32] = {};
    for (int dc = 0; dc < ND; dc += DT) {
      int nd = ND - dc < DT ? ND - dc : DT;
      for (int idx = tid; idx < 32*DT; idx += 64) {
        int dl = idx & (DT-1), c = idx >> 7;
        float kk = 0.f, vv = 0.f;
        if (dl < nd) {
          kk = Kp[(size_t)c*ND + dc+dl];
          vv = Vp[(size_t)c*ND + dc+dl];
        }
        sK[dl][c] = kk; sV[dl][c] = vv;
      }
      __syncthreads();
      for (int dl = 0; dl < nd; dl++) {
        float a0=0,a1=0,a2=0,a3=0, b0=0,b1=0,b2=0,b3=0;
        #pragma unroll
        for (int c4 = 0; c4 < 8; c4++) {
          float4 kv = *(const float4*)&sK[dl][c4*4];
          a0 += qra[c4*4+0]*kv.x; a1 += qra[c4*4+1]*kv.y;
          a2 += qra[c4*4+2]*kv.z; a3 += qra[c4*4+3]*kv.w;
          b0 += qrb[c4*4+0]*kv.x; b1 += qrb[c4*4+1]*kv.y;
          b2 += qrb[c4*4+2]*kv.z; b3 += qrb[c4*4+3]*kv.w;
        }
        float scA = (a0+a1)+(a2+a3);
        float scB = (b0+b1)+(b2+b3);
        if (scA > mA) {
          float corr = __expf(mA - scA); sA *= corr;
          #pragma unroll
          for (int c = 0; c < 32; c++) accA[c] *= corr;
          mA = scA;
        }
        float eA = __expf(scA - mA); sA += eA;
        if (scB > mB) {
          float corr = __expf(mB - scB); sB *= corr;
          #pragma unroll
          for (int c = 0; c < 32; c++) accB[c] *= corr;
          mB = scB;
        }
        float eB = __expf(scB - mB); sB += eB;
        #pragma unroll
        for (int c4 = 0; c4 < 8; c4++) {
          float4 vv = *(const float4*)&sV[dl][c4*4];
          accA[c4*4+0] += eA*vv.x; accA[c4*4+1] += eA*vv.y;
          accA[c4*4+2] += eA*vv.z; accA[c4*4+3] += eA*vv.w;
          accB[c4*4+0] += eB*vv.x; accB[c4*4+1] += eB*vv.y;
          accB[c4*4+2] += eB*vv.z; accB[c4*4+3] += eB*vv.w;
        }
      }
      __syncthreads();
    }
    float invA = 1.f/sA, invB = 1.f/sB;
    #pragma unroll
    for (int c = 0; c < 32; c++) {
      if (qA < NPIX) ab[((size_t)n*AA + h*HCH + c)*NPIX + qA] = accA[c]*invA;
      if (qB < NPIX) ab[((size_t)n*AA + h*HCH + c)*NPIX + qB] = accB[c]*invB;
    }
}

// ---------------- fused 3-gate GEMM (i,g,o) + LSTM nonlinearity ----------------
__global__ __launch_bounds__(256) void k_gates(const float* __restrict__ a,
        const float* __restrict__ xin, const float* __restrict__ w_ga,
        const float* __restrict__ w_gx, const float* __restrict__ b_g,
        float* __restrict__ hn) {
    __shared__ float Xs[BK][LPAD];
    __shared__ float Ws[3][BK][LPAD];
    int tid = threadIdx.x;
    int tx = tid & 15, ty = tid >> 4;
    int p0 = blockIdx.x * 64, m0 = blockIdx.y * 64, n = blockIdx.z;
    float acc[3][4][4] = {};
    for (int k0 = 0; k0 < 512; k0 += BK) {
      const float* src  = (k0 < 256) ? a    : xin;
      const float* wsrc = (k0 < 256) ? w_ga : w_gx;
      int chb = (k0 < 256) ? k0 : k0 - 256;
      for (int idx = tid; idx < 2048; idx += 256) {
        int cc = idx >> 6, pp = idx & 63;
        int p = p0 + pp;
        Xs[cc][pp] = (p < NPIX) ? src[((size_t)n*256 + chb+cc)*NPIX + p] : 0.f;
      }
      for (int idx = tid; idx < 6144; idx += 256) {
        int g = idx >> 11;
        int rem = idx & 2047;
        int aa = rem >> 5, cc = rem & 31;
        int gb = (g == 0) ? 0 : (g == 1) ? 512 : 768;
        Ws[g][cc][aa] = wsrc[(size_t)(gb + m0+aa)*256 + chb+cc];
      }
      __syncthreads();
      #pragma unroll
      for (int cc = 0; cc < BK; cc++) {
        float4 xv = *(const float4*)&Xs[cc][tx*4];
        #pragma unroll
        for (int g = 0; g < 3; g++) {
          float4 wv = *(const float4*)&Ws[g][cc][ty*4];
          acc[g][0][0] += wv.x*xv.x; acc[g][0][1] += wv.x*xv.y; acc[g][0][2] += wv.x*xv.z; acc[g][0][3] += wv.x*xv.w;
          acc[g][1][0] += wv.y*xv.x; acc[g][1][1] += wv.y*xv.y; acc[g][1][2] += wv.y*xv.z; acc[g][1][3] += wv.y*xv.w;
          acc[g][2][0] += wv.z*xv.x; acc[g][2][1] += wv.z*xv.y; acc[g][2][2] += wv.z*xv.z; acc[g][2][3] += wv.z*xv.w;
          acc[g][3][0] += wv.w*xv.x; acc[g][3][1] += wv.w*xv.y; acc[g][3][2] += wv.w*xv.z; acc[g][3][3] += wv.w*xv.w;
        }
      }
      __syncthreads();
    }
    #pragma unroll
    for (int j = 0; j < 4; j++) {
      int r = m0 + ty*4 + j;
      float bi = b_g[r], bg = b_g[512 + r], bo = b_g[768 + r];
      #pragma unroll
      for (int i = 0; i < 4; i++) {
        int p = p0 + tx*4 + i;
        if (p < NPIX) {
          float gi = acc[0][j][i] + bi;
          float gg = acc[1][j][i] + bg;
          float go = acc[2][j][i] + bo;
          float si = 1.f / (1.f + __expf(-gi));
          float so = 1.f / (1.f + __expf(-go));
          float cv = si * tanhf(gg);
          hn[((size_t)n*RR + r)*NPIX + p] = so * tanhf(cv);
        }
      }
    }
}

extern "C" void kernel_launch(void* const* d_in, const int* in_sizes, int n_in,
                              void* d_out, int out_size, void* d_ws, size_t ws_size,
                              hipStream_t stream) {
    const float* x     = (const float*)d_in[0];
    const float* w_in  = (const float*)d_in[1];
    const float* b_in  = (const float*)d_in[2];
    const float* w_qx  = (const float*)d_in[3];
    const float* w_kx  = (const float*)d_in[5];
    const float* w_vx  = (const float*)d_in[7];
    const float* w_ga  = (const float*)d_in[9];
    const float* b_g   = (const float*)d_in[10];
    const float* w_gx  = (const float*)d_in[11];
    const float* w_out = (const float*)d_in[13];
    const float* b_out = (const float*)d_in[14];
    float* out = (float*)d_out;

    float* ws = (float*)d_ws;
    const size_t np = (size_t)NN * RR * NPIX;   // 2,654,208
    const size_t nd = (size_t)NN * AA * ND;     // 2,367,488
    float* xin = ws;
    float* qb  = xin + np;
    float* kb  = qb + np;
    float* vb  = kb + nd;
    float* ab  = vb + nd;
    float* hnb = qb;   // q dead after attention

    dim3 blk(256);
    int pt = (NPIX + 63) / 64;  // 21
    int pv = (ND + 63) / 64;    // 19

    k_gemm1x1       <<<dim3(pt, 4, NN), blk, 0, stream>>>(x, w_in, b_in, xin, CI);
    k_conv3x3<true> <<<dim3(pt, 4, NN), blk, 0, stream>>>(xin, w_qx, qb);
    k_conv3x3<false><<<dim3(pv, 4, NN), blk, 0, stream>>>(xin, w_kx, kb);
    k_conv3x3<false><<<dim3(pv, 4, NN), blk, 0, stream>>>(xin, w_vx, vb);
    k_attn          <<<dim3(11, NHEADS, NN), dim3(64), 0, stream>>>(qb, kb, vb, ab);
    k_gates         <<<dim3(pt, 4, NN), blk, 0, stream>>>(ab, xin, w_ga, w_gx, b_g, hnb);
    k_gemm1x1       <<<dim3(pt, 4, NN), blk, 0, stream>>>(hnb, w_out, b_out, out, RR);
}

// Round 3
// 379.935 us; speedup vs baseline: 55.1222x; 5.9899x over previous
//
#include <hip/hip_runtime.h>
#include <math.h>

typedef unsigned int u32;
typedef unsigned short u16;
typedef unsigned long long u64;
typedef __attribute__((ext_vector_type(8))) __bf16 bf8;
typedef __attribute__((ext_vector_type(4))) float f4;

#define MFMA(a,b,c) __builtin_amdgcn_mfma_f32_16x16x32_bf16(a,b,c,0,0,0)

static __device__ __forceinline__ u32 cvtpk(float lo, float hi) {
  u32 r; asm("v_cvt_pk_bf16_f32 %0, %1, %2" : "=v"(r) : "v"(lo), "v"(hi));
  return r;
}
static __device__ __forceinline__ u16 f2b(float x) { return (u16)cvtpk(x, 0.f); }
static __device__ __forceinline__ float sigm(float x) { return 1.f/(1.f+__expf(-x)); }

// ---------------- weight transforms (bf16, once per call) ----------------
__global__ __launch_bounds__(256) void k_cvt(const float* __restrict__ in,
        u16* __restrict__ out, int n) {
  int i = blockIdx.x*256 + threadIdx.x;
  if (i < n) out[i] = f2b(in[i]);
}
// conv weight [256][256*9] -> tap-major [9][256][256]
__global__ __launch_bounds__(256) void k_wt3(const float* __restrict__ w,
        u16* __restrict__ wt) {
  int i = blockIdx.x*256 + threadIdx.x;          // over [9][256][256]
  int tap = i >> 16, mm = (i & 65535) >> 8, rr = i & 255;
  wt[i] = f2b(w[(size_t)mm*2304 + rr*9 + tap]);
}
// gates: [3 gates i,g,o][256 rows][512 k] (k<256: w_ga, else w_gx); skip f-gate
__global__ __launch_bounds__(256) void k_wtg(const float* __restrict__ w_ga,
        const float* __restrict__ w_gx, u16* __restrict__ wg) {
  int i = blockIdx.x*256 + threadIdx.x;          // over [3][256][512]
  int g = i >> 17, rem = i & 131071, rr = rem >> 9, kk = rem & 511;
  int gb = (g == 0) ? 0 : (g == 1) ? 512 : 768;
  float v = (kk < 256) ? w_ga[(size_t)(gb+rr)*256 + kk]
                       : w_gx[(size_t)(gb+rr)*256 + kk - 256];
  wg[i] = f2b(v);
}

// ---------------- xin GEMM: M=256,K=128 over x fp32 ----------------
__global__ __launch_bounds__(256,2) void k_xin(const float* __restrict__ x,
        const u16* __restrict__ wb, const float* __restrict__ bias,
        u16* __restrict__ out) {
  __shared__ u16 Xs[128][40];
  __shared__ u16 Ws[128][40];
  int tid = threadIdx.x, lane = tid & 63, wid = tid >> 6;
  int p0 = blockIdx.x*128, m0 = blockIdx.y*128, n = blockIdx.z;
  int pcol = tid & 127, rg = tid >> 7;
  int p = p0 + pcol;
  const float* src = x + (size_t)n*128*1296;
  f4 z = {0.f,0.f,0.f,0.f};
  f4 acc[4][4];
  #pragma unroll
  for (int i=0;i<4;i++) { acc[i][0]=z; acc[i][1]=z; acc[i][2]=z; acc[i][3]=z; }
  int wm = (wid & 1)*64, wp = (wid >> 1)*64;
  for (int k0 = 0; k0 < 128; k0 += 32) {
    #pragma unroll
    for (int it = 0; it < 8; it++) {
      int rp = it*2 + rg, rr = k0 + rp*2;
      float a = 0.f, b = 0.f;
      if (p < 1296) { a = src[(size_t)rr*1296+p]; b = src[(size_t)(rr+1)*1296+p]; }
      ((u32*)&Xs[pcol][0])[rp] = cvtpk(a, b);
    }
    #pragma unroll
    for (int j2 = 0; j2 < 8; j2++) {
      int idx = tid + j2*256, mm = idx >> 4, rc = idx & 15;
      ((u32*)&Ws[mm][0])[rc] = *(const u32*)&wb[(size_t)(m0+mm)*128 + k0 + rc*2];
    }
    __syncthreads();
    bf8 af[4], bx[4];
    #pragma unroll
    for (int mt=0;mt<4;mt++) af[mt] = *(bf8*)&Ws[wm + mt*16 + (lane&15)][8*(lane>>4)];
    #pragma unroll
    for (int pt=0;pt<4;pt++) bx[pt] = *(bf8*)&Xs[wp + pt*16 + (lane&15)][8*(lane>>4)];
    #pragma unroll
    for (int mt=0;mt<4;mt++)
      #pragma unroll
      for (int pt=0;pt<4;pt++)
        acc[mt][pt] = MFMA(af[mt], bx[pt], acc[mt][pt]);
    __syncthreads();
  }
  #pragma unroll
  for (int mt=0;mt<4;mt++)
    #pragma unroll
    for (int pt=0;pt<4;pt++)
      #pragma unroll
      for (int j=0;j<4;j++) {
        int m = m0 + wm + mt*16 + (lane>>4)*4 + j;
        int pp = p0 + wp + pt*16 + (lane&15);
        if (pp < 1296) out[((size_t)n*256 + m)*1296 + pp] = f2b(acc[mt][pt][j] + bias[m]);
      }
}

// ---------------- fused q/k/v 3x3 convs, tap-major implicit GEMM ----------------
__global__ __launch_bounds__(256,2) void k_conv3(const u16* __restrict__ xin,
        const u16* __restrict__ wq, const u16* __restrict__ wk, const u16* __restrict__ wv,
        u16* __restrict__ qb, u16* __restrict__ kb, u16* __restrict__ vb) {
  __shared__ u16 Xs[128][40];
  __shared__ u16 Ws[128][40];
  int tid = threadIdx.x, lane = tid & 63, wid = tid >> 6;
  int kind = blockIdx.y >> 1;
  int m0 = (blockIdx.y & 1)*128;
  int n = blockIdx.z;
  int P  = (kind == 0) ? 1296 : 1156;
  int WO = (kind == 0) ? 36 : 34;
  int pad = (kind == 0) ? 1 : 0;
  int p0 = blockIdx.x*128;
  if (p0 >= P) return;
  const u16* wt = (kind==0) ? wq : (kind==1) ? wk : wv;
  u16* dst = (kind==0) ? qb : (kind==1) ? kb : vb;
  const u16* src = xin + (size_t)n*256*1296;
  int pcol = tid & 127, rg = tid >> 7;
  int p = p0 + pcol;
  int py = 0, px = 0;
  if (p < P) { py = p / WO; px = p % WO; }
  f4 z = {0.f,0.f,0.f,0.f};
  f4 acc[4][4];
  #pragma unroll
  for (int i=0;i<4;i++) { acc[i][0]=z; acc[i][1]=z; acc[i][2]=z; acc[i][3]=z; }
  int wm = (wid & 1)*64, wp = (wid >> 1)*64;
  for (int tap = 0; tap < 9; tap++) {
    int dy = tap/3 - pad, dx = tap%3 - pad;
    int sy = py + dy, sx = px + dx;
    bool ok = (p < P) && (sy >= 0) && (sy < 36) && (sx >= 0) && (sx < 36);
    int soff = sy*36 + sx;
    const u16* wtt = wt + tap*65536;
    for (int r0 = 0; r0 < 256; r0 += 32) {
      #pragma unroll
      for (int it = 0; it < 8; it++) {
        int rp = it*2 + rg, rr = r0 + rp*2;
        u32 v = 0;
        if (ok) {
          u32 a = src[(size_t)rr*1296 + soff];
          u32 b = src[(size_t)(rr+1)*1296 + soff];
          v = a | (b << 16);
        }
        ((u32*)&Xs[pcol][0])[rp] = v;
      }
      #pragma unroll
      for (int j2 = 0; j2 < 8; j2++) {
        int idx = tid + j2*256, mm = idx >> 4, rc = idx & 15;
        ((u32*)&Ws[mm][0])[rc] = *(const u32*)&wtt[(size_t)(m0+mm)*256 + r0 + rc*2];
      }
      __syncthreads();
      bf8 af[4], bx[4];
      #pragma unroll
      for (int mt=0;mt<4;mt++) af[mt] = *(bf8*)&Ws[wm + mt*16 + (lane&15)][8*(lane>>4)];
      #pragma unroll
      for (int pt=0;pt<4;pt++) bx[pt] = *(bf8*)&Xs[wp + pt*16 + (lane&15)][8*(lane>>4)];
      #pragma unroll
      for (int mt=0;mt<4;mt++)
        #pragma unroll
        for (int pt=0;pt<4;pt++)
          acc[mt][pt] = MFMA(af[mt], bx[pt], acc[mt][pt]);
      __syncthreads();
    }
  }
  #pragma unroll
  for (int mt=0;mt<4;mt++)
    #pragma unroll
    for (int pt=0;pt<4;pt++)
      #pragma unroll
      for (int j=0;j<4;j++) {
        int m = m0 + wm + mt*16 + (lane>>4)*4 + j;
        int pp = p0 + wp + pt*16 + (lane&15);
        if (pp < P) dst[((size_t)n*256 + m)*P + pp] = f2b(acc[mt][pt][j]);
      }
}

// ---------------- flash attention, MFMA, online softmax ----------------
__global__ __launch_bounds__(256,2) void k_attn(const u16* __restrict__ qbf,
        const u16* __restrict__ kbf, const u16* __restrict__ vbf, u16* __restrict__ abf) {
  __shared__ u16 Qs[128][40];
  __shared__ u16 Ks[64][40];
  __shared__ u16 Vs[2][32][40];
  __shared__ u16 Ps[4][2][32][40];
  int tid = threadIdx.x, lane = tid & 63, wid = tid >> 6;
  int h = blockIdx.y, n = blockIdx.z;
  int q0 = blockIdx.x*128;
  const u16* Qp = qbf + ((size_t)n*256 + h*32)*1296;
  const u16* Kp = kbf + ((size_t)n*256 + h*32)*1156;
  const u16* Vp = vbf + ((size_t)n*256 + h*32)*1156;
  #pragma unroll
  for (int j = 0; j < 8; j++) {
    int idx = tid + j*256, qq = idx >> 4, cp = idx & 15;
    int gq = q0 + qq; u32 v = 0;
    if (gq < 1296)
      v = (u32)Qp[(size_t)(2*cp)*1296 + gq] | ((u32)Qp[(size_t)(2*cp+1)*1296 + gq] << 16);
    ((u32*)&Qs[qq][0])[cp] = v;
  }
  f4 z = {0.f,0.f,0.f,0.f};
  float mx[2] = {-1e30f, -1e30f}, ls[2] = {0.f, 0.f};
  f4 accO[2][2] = {{z,z},{z,z}};
  int wq = wid*32;
  __syncthreads();
  for (int d0 = 0; d0 < 1156; d0 += 64) {
    #pragma unroll
    for (int j = 0; j < 4; j++) {
      int idx = tid + j*256, dd = idx >> 4, cp = idx & 15;
      int gd = d0 + dd; u32 v = 0;
      if (gd < 1156)
        v = (u32)Kp[(size_t)(2*cp)*1156 + gd] | ((u32)Kp[(size_t)(2*cp+1)*1156 + gd] << 16);
      ((u32*)&Ks[dd][0])[cp] = v;
    }
    #pragma unroll
    for (int j = 0; j < 4; j++) {
      int idx = tid + j*256, half = idx >> 9, rem = idx & 511;
      int cc = rem >> 4, dp = rem & 15;
      int gd = d0 + half*32 + dp*2; u32 v = 0;
      if (gd < 1156) v = *(const u32*)&Vp[(size_t)cc*1156 + gd];
      ((u32*)&Vs[half][cc][0])[dp] = v;
    }
    __syncthreads();
    bf8 ak[4], bq[2];
    #pragma unroll
    for (int dt=0;dt<4;dt++) ak[dt] = *(bf8*)&Ks[dt*16 + (lane&15)][8*(lane>>4)];
    #pragma unroll
    for (int qt=0;qt<2;qt++) bq[qt] = *(bf8*)&Qs[wq + qt*16 + (lane&15)][8*(lane>>4)];
    f4 s[2][4];
    #pragma unroll
    for (int qt=0;qt<2;qt++)
      #pragma unroll
      for (int dt=0;dt<4;dt++)
        s[qt][dt] = MFMA(ak[dt], bq[qt], z);
    bool tail = (d0 + 64 > 1156);
    #pragma unroll
    for (int qt=0;qt<2;qt++) {
      if (tail) {
        #pragma unroll
        for (int dt=0;dt<4;dt++)
          #pragma unroll
          for (int j=0;j<4;j++)
            if (d0 + dt*16 + (lane>>4)*4 + j >= 1156) s[qt][dt][j] = -1e30f;
      }
      float tm = -1e30f;
      #pragma unroll
      for (int dt=0;dt<4;dt++)
        #pragma unroll
        for (int j=0;j<4;j++) tm = fmaxf(tm, s[qt][dt][j]);
      tm = fmaxf(tm, __shfl_xor(tm, 16));
      tm = fmaxf(tm, __shfl_xor(tm, 32));
      float nm = fmaxf(mx[qt], tm);
      float corr = __expf(mx[qt] - nm);
      mx[qt] = nm;
      float rs = 0.f;
      #pragma unroll
      for (int dt=0;dt<4;dt++)
        #pragma unroll
        for (int j=0;j<4;j++) {
          float e = __expf(s[qt][dt][j] - nm);
          s[qt][dt][j] = e; rs += e;
        }
      rs += __shfl_xor(rs, 16); rs += __shfl_xor(rs, 32);
      ls[qt] = ls[qt]*corr + rs;
      accO[0][qt] *= corr; accO[1][qt] *= corr;
      #pragma unroll
      for (int dt=0;dt<4;dt++) {
        u32 lo_ = cvtpk(s[qt][dt][0], s[qt][dt][1]);
        u32 hi_ = cvtpk(s[qt][dt][2], s[qt][dt][3]);
        u64 pk = (u64)lo_ | ((u64)hi_ << 32);
        *(u64*)&Ps[wid][dt>>1][qt*16 + (lane&15)][(dt&1)*16 + (lane>>4)*4] = pk;
      }
    }
    #pragma unroll
    for (int kt=0;kt<2;kt++) {
      bf8 av0 = *(bf8*)&Vs[kt][(lane&15)][8*(lane>>4)];
      bf8 av1 = *(bf8*)&Vs[kt][16 + (lane&15)][8*(lane>>4)];
      bf8 bp0 = *(bf8*)&Ps[wid][kt][(lane&15)][8*(lane>>4)];
      bf8 bp1 = *(bf8*)&Ps[wid][kt][16 + (lane&15)][8*(lane>>4)];
      accO[0][0] = MFMA(av0, bp0, accO[0][0]);
      accO[0][1] = MFMA(av0, bp1, accO[0][1]);
      accO[1][0] = MFMA(av1, bp0, accO[1][0]);
      accO[1][1] = MFMA(av1, bp1, accO[1][1]);
    }
    __syncthreads();
  }
  #pragma unroll
  for (int qt=0;qt<2;qt++) {
    float inv = 1.f / ls[qt];
    #pragma unroll
    for (int mt=0;mt<2;mt++)
      #pragma unroll
      for (int j=0;j<4;j++) {
        int c = h*32 + mt*16 + (lane>>4)*4 + j;
        int gq = q0 + wq + qt*16 + (lane&15);
        if (gq < 1296) abf[((size_t)n*256 + c)*1296 + gq] = f2b(accO[mt][qt][j] * inv);
      }
  }
}

// ---------------- fused gates GEMM (i,g,o; K=512) + LSTM nonlinearity ----------------
__global__ __launch_bounds__(256,2) void k_gates(const u16* __restrict__ abf,
        const u16* __restrict__ xin, const u16* __restrict__ wg,
        const float* __restrict__ b_g, u16* __restrict__ hn) {
  __shared__ u16 Xs[128][40];
  __shared__ u16 Wg[3][64][40];
  int tid = threadIdx.x, lane = tid & 63, wid = tid >> 6;
  int p0 = blockIdx.x*128, m0 = blockIdx.y*64, n = blockIdx.z;
  int pcol = tid & 127, rg = tid >> 7;
  int p = p0 + pcol;
  f4 z = {0.f,0.f,0.f,0.f};
  f4 acc[3][2][4];
  #pragma unroll
  for (int g=0;g<3;g++)
    #pragma unroll
    for (int mt=0;mt<2;mt++) { acc[g][mt][0]=z; acc[g][mt][1]=z; acc[g][mt][2]=z; acc[g][mt][3]=z; }
  int wm = (wid & 1)*32, wp = (wid >> 1)*64;
  for (int k0 = 0; k0 < 512; k0 += 32) {
    const u16* src = ((k0 < 256) ? abf : xin) + (size_t)n*256*1296 + (size_t)(k0 & 255)*1296;
    #pragma unroll
    for (int it = 0; it < 8; it++) {
      int rp = it*2 + rg, rr = rp*2;
      u32 v = 0;
      if (p < 1296)
        v = (u32)src[(size_t)rr*1296 + p] | ((u32)src[(size_t)(rr+1)*1296 + p] << 16);
      ((u32*)&Xs[pcol][0])[rp] = v;
    }
    #pragma unroll
    for (int j2 = 0; j2 < 12; j2++) {
      int idx = tid + j2*256;
      int g = idx >> 10, rem = idx & 1023, mm = rem >> 4, kc = rem & 15;
      ((u32*)&Wg[g][mm][0])[kc] =
          *(const u32*)&wg[(size_t)g*131072 + (size_t)(m0+mm)*512 + k0 + kc*2];
    }
    __syncthreads();
    bf8 bx[4];
    #pragma unroll
    for (int pt=0;pt<4;pt++) bx[pt] = *(bf8*)&Xs[wp + pt*16 + (lane&15)][8*(lane>>4)];
    #pragma unroll
    for (int g=0;g<3;g++)
      #pragma unroll
      for (int mt=0;mt<2;mt++) {
        bf8 af = *(bf8*)&Wg[g][wm + mt*16 + (lane&15)][8*(lane>>4)];
        #pragma unroll
        for (int pt=0;pt<4;pt++)
          acc[g][mt][pt] = MFMA(af, bx[pt], acc[g][mt][pt]);
      }
    __syncthreads();
  }
  #pragma unroll
  for (int mt=0;mt<2;mt++)
    #pragma unroll
    for (int pt=0;pt<4;pt++)
      #pragma unroll
      for (int j=0;j<4;j++) {
        int r = m0 + wm + mt*16 + (lane>>4)*4 + j;
        int pp = p0 + wp + pt*16 + (lane&15);
        if (pp < 1296) {
          float gi = acc[0][mt][pt][j] + b_g[r];
          float gg = acc[1][mt][pt][j] + b_g[512 + r];
          float go = acc[2][mt][pt][j] + b_g[768 + r];
          float hv = sigm(go) * tanhf(sigm(gi) * tanhf(gg));
          hn[((size_t)n*256 + r)*1296 + pp] = f2b(hv);
        }
      }
}

// ---------------- out GEMM: M=256,K=256 over hn bf16, out fp32 ----------------
__global__ __launch_bounds__(256,2) void k_out(const u16* __restrict__ hn,
        const u16* __restrict__ wb, const float* __restrict__ bias,
        float* __restrict__ out) {
  __shared__ u16 Xs[128][40];
  __shared__ u16 Ws[128][40];
  int tid = threadIdx.x, lane = tid & 63, wid = tid >> 6;
  int p0 = blockIdx.x*128, m0 = blockIdx.y*128, n = blockIdx.z;
  int pcol = tid & 127, rg = tid >> 7;
  int p = p0 + pcol;
  const u16* src = hn + (size_t)n*256*1296;
  f4 z = {0.f,0.f,0.f,0.f};
  f4 acc[4][4];
  #pragma unroll
  for (int i=0;i<4;i++) { acc[i][0]=z; acc[i][1]=z; acc[i][2]=z; acc[i][3]=z; }
  int wm = (wid & 1)*64, wp = (wid >> 1)*64;
  for (int k0 = 0; k0 < 256; k0 += 32) {
    #pragma unroll
    for (int it = 0; it < 8; it++) {
      int rp = it*2 + rg, rr = k0 + rp*2;
      u32 v = 0;
      if (p < 1296)
        v = (u32)src[(size_t)rr*1296 + p] | ((u32)src[(size_t)(rr+1)*1296 + p] << 16);
      ((u32*)&Xs[pcol][0])[rp] = v;
    }
    #pragma unroll
    for (int j2 = 0; j2 < 8; j2++) {
      int idx = tid + j2*256, mm = idx >> 4, rc = idx & 15;
      ((u32*)&Ws[mm][0])[rc] = *(const u32*)&wb[(size_t)(m0+mm)*256 + k0 + rc*2];
    }
    __syncthreads();
    bf8 af[4], bx[4];
    #pragma unroll
    for (int mt=0;mt<4;mt++) af[mt] = *(bf8*)&Ws[wm + mt*16 + (lane&15)][8*(lane>>4)];
    #pragma unroll
    for (int pt=0;pt<4;pt++) bx[pt] = *(bf8*)&Xs[wp + pt*16 + (lane&15)][8*(lane>>4)];
    #pragma unroll
    for (int mt=0;mt<4;mt++)
      #pragma unroll
      for (int pt=0;pt<4;pt++)
        acc[mt][pt] = MFMA(af[mt], bx[pt], acc[mt][pt]);
    __syncthreads();
  }
  #pragma unroll
  for (int mt=0;mt<4;mt++)
    #pragma unroll
    for (int pt=0;pt<4;pt++)
      #pragma unroll
      for (int j=0;j<4;j++) {
        int m = m0 + wm + mt*16 + (lane>>4)*4 + j;
        int pp = p0 + wp + pt*16 + (lane&15);
        if (pp < 1296) out[((size_t)n*256 + m)*1296 + pp] = acc[mt][pt][j] + bias[m];
      }
}

extern "C" void kernel_launch(void* const* d_in, const int* in_sizes, int n_in,
                              void* d_out, int out_size, void* d_ws, size_t ws_size,
                              hipStream_t stream) {
  const float* x     = (const float*)d_in[0];
  const float* w_in  = (const float*)d_in[1];
  const float* b_in  = (const float*)d_in[2];
  const float* w_qx  = (const float*)d_in[3];
  const float* w_kx  = (const float*)d_in[5];
  const float* w_vx  = (const float*)d_in[7];
  const float* w_ga  = (const float*)d_in[9];
  const float* b_g   = (const float*)d_in[10];
  const float* w_gx  = (const float*)d_in[11];
  const float* w_out = (const float*)d_in[13];
  const float* b_out = (const float*)d_in[14];
  float* out = (float*)d_out;

  u16* ws = (u16*)d_ws;
  size_t o = 0;
  u16* xin_bf = ws + o; o += 2654208;   // [8][256][1296]
  u16* qbuf   = ws + o; o += 2654208;
  u16* kbuf   = ws + o; o += 2367488;   // [8][256][1156]
  u16* vbuf   = ws + o; o += 2367488;
  u16* abuf   = ws + o; o += 2654208;
  u16* hnb    = ws + o; o += 2654208;
  u16* wqT    = ws + o; o += 589824;    // [9][256][256]
  u16* wkT    = ws + o; o += 589824;
  u16* wvT    = ws + o; o += 589824;
  u16* wgT    = ws + o; o += 393216;    // [3][256][512]
  u16* winb   = ws + o; o += 32768;
  u16* woutb  = ws + o; o += 65536;

  k_cvt<<<128, 256, 0, stream>>>(w_in, winb, 32768);
  k_cvt<<<256, 256, 0, stream>>>(w_out, woutb, 65536);
  k_wt3<<<2304, 256, 0, stream>>>(w_qx, wqT);
  k_wt3<<<2304, 256, 0, stream>>>(w_kx, wkT);
  k_wt3<<<2304, 256, 0, stream>>>(w_vx, wvT);
  k_wtg<<<1536, 256, 0, stream>>>(w_ga, w_gx, wgT);

  k_xin  <<<dim3(11,2,8), 256, 0, stream>>>(x, winb, b_in, xin_bf);
  k_conv3<<<dim3(11,6,8), 256, 0, stream>>>(xin_bf, wqT, wkT, wvT, qbuf, kbuf, vbuf);
  k_attn <<<dim3(11,8,8), 256, 0, stream>>>(qbuf, kbuf, vbuf, abuf);
  k_gates<<<dim3(11,4,8), 256, 0, stream>>>(abuf, xin_bf, wgT, b_g, hnb);
  k_out  <<<dim3(11,2,8), 256, 0, stream>>>(hnb, woutb, b_out, out);
}